// Round 2
// baseline (410.067 us; speedup 1.0000x reference)
//
#include <hip/hip_runtime.h>

#define NN 50000
#define D 128
#define EE 600000
#define R 8
#define NR (NN * R)            /* segments, key = dst*R + rel (node-major) */
#define SCAN_CHUNK 1024
#define NSB ((NR + SCAN_CHUNK - 1) / SCAN_CHUNK) /* 391 */
#define KT 36                  /* K tiles: (8*128 + 128)/32 */

typedef unsigned short u16;
typedef unsigned int u32;
typedef __attribute__((ext_vector_type(8))) short bf16x8;
typedef __attribute__((ext_vector_type(4))) float f32x4;

__device__ inline u16 f2bf(float f) {
    union { float f; u32 u; } v; v.f = f;
    return (u16)((v.u + 0x7FFFu + ((v.u >> 16) & 1u)) >> 16);
}
__device__ inline float bf2f(u16 h) {
    union { u32 u; float f; } v; v.u = ((u32)h) << 16;
    return v.f;
}

// ---- histogram per segment key = dst*R + rel ----
__global__ __launch_bounds__(256) void hist_kernel(const int* __restrict__ dst,
                                                   const int* __restrict__ et,
                                                   int* __restrict__ cnt, int E) {
    int e = blockIdx.x * 256 + threadIdx.x;
    if (e < E) atomicAdd(&cnt[dst[e] * R + et[e]], 1);
}

// ---- exclusive scan pass A ----
__global__ __launch_bounds__(256) void scanA(const int* __restrict__ cnt,
                                             int* __restrict__ off,
                                             int* __restrict__ bsum) {
    __shared__ int ts[256];
    const int b = blockIdx.x, t = threadIdx.x;
    const int base = b * SCAN_CHUNK + t * 4;
    int v0 = 0, v1 = 0, v2 = 0, v3 = 0;
    if (base + 3 < NR) {
        int4 q = *(const int4*)(cnt + base);
        v0 = q.x; v1 = q.y; v2 = q.z; v3 = q.w;
    } else {
        if (base < NR) v0 = cnt[base];
        if (base + 1 < NR) v1 = cnt[base + 1];
        if (base + 2 < NR) v2 = cnt[base + 2];
    }
    const int s = v0 + v1 + v2 + v3;
    ts[t] = s;
    __syncthreads();
    for (int d = 1; d < 256; d <<= 1) {
        int x = (t >= d) ? ts[t - d] : 0;
        __syncthreads();
        ts[t] += x;
        __syncthreads();
    }
    const int excl = ts[t] - s;
    if (base < NR) off[base] = excl;
    if (base + 1 < NR) off[base + 1] = excl + v0;
    if (base + 2 < NR) off[base + 2] = excl + v0 + v1;
    if (base + 3 < NR) off[base + 3] = excl + v0 + v1 + v2;
    if (t == 255) bsum[b] = ts[255];
}

// ---- scan pass B+C fused ----
__global__ __launch_bounds__(256) void scanBC(int* __restrict__ off,
                                              int* __restrict__ cursor,
                                              const int* __restrict__ bsum) {
    __shared__ int red[256];
    const int b = blockIdx.x, t = threadIdx.x;
    int p = 0;
    for (int i = t; i < b; i += 256) p += bsum[i];
    red[t] = p;
    __syncthreads();
    for (int d = 128; d > 0; d >>= 1) {
        if (t < d) red[t] += red[t + d];
        __syncthreads();
    }
    const int add = red[0];
    const int base = b * SCAN_CHUNK + t * 4;
#pragma unroll
    for (int j = 0; j < 4; ++j)
        if (base + j < NR) {
            int v = off[base + j] + add;
            off[base + j] = v;
            cursor[base + j] = v;
        }
    if (b == 0 && t == 0) off[NR] = EE;
}

// ---- place: ONE packed u32 store per edge: (src << 3) | rel  (src < 2^16) ----
__global__ __launch_bounds__(256) void place_kernel(const int* __restrict__ src,
                                                    const int* __restrict__ dst,
                                                    const int* __restrict__ et,
                                                    int* __restrict__ cursor,
                                                    u32* __restrict__ epk, int E) {
    int e = blockIdx.x * 256 + threadIdx.x;
    if (e < E) {
        int r = et[e];
        int key = dst[e] * R + r;
        int p = atomicAdd(&cursor[key], 1);
        epk[p] = ((u32)src[e] << 3) | (u32)r;
    }
}

// ---- pack both layers' B = [W_1..W_8; root] (K=1152, 128 cols) into MFMA
// B-frag order: [kt(36)][g(8)][lane(64)][j(8)], col = g*16+(lane&15),
// k = kt*32+(lane>>4)*8+j. Also zero cnt_i. ----
__global__ __launch_bounds__(256) void bprep2_kernel(const float* __restrict__ w1,
                                                     const float* __restrict__ root1,
                                                     u16* __restrict__ Bf1,
                                                     const float* __restrict__ w2,
                                                     const float* __restrict__ root2,
                                                     u16* __restrict__ Bf2,
                                                     int4* __restrict__ cntz) {
    int gidx = blockIdx.x * 256 + threadIdx.x;  // over 2*36*8*64 = 36864
    for (int i = gidx; i < NR / 4; i += 36864)
        cntz[i] = make_int4(0, 0, 0, 0);
    if (gidx >= 2 * KT * 8 * 64) return;
    const int layer = gidx / (KT * 8 * 64);
    const int idx = gidx - layer * (KT * 8 * 64);
    const float* w = layer ? w2 : w1;
    const float* root = layer ? root2 : root1;
    u16* Bfrag = layer ? Bf2 : Bf1;
    const int lane = idx & 63;
    const int g = (idx >> 6) & 7;
    const int kt = idx >> 9;  // 0..35
    const int col = g * 16 + (lane & 15);
    const int kbase = kt * 32 + (lane >> 4) * 8;
    u16* o = Bfrag + (size_t)idx * 8;
#pragma unroll
    for (int j = 0; j < 8; ++j) {
        const int k = kbase + j;
        float v = (k < R * D) ? w[(size_t)(k >> 7) * (D * D) + (size_t)(k & 127) * D + col]
                              : root[(size_t)(k - R * D) * D + col];
        o[j] = f2bf(v);
    }
}

// ---- cast x fp32 -> packed bf16 pairs [N][64] u32 ----
__global__ __launch_bounds__(256) void xcast_kernel(const float4* __restrict__ x,
                                                    u32* __restrict__ xb) {
    int i = blockIdx.x * 256 + threadIdx.x;  // over N*32
    if (i < NN * 32) {
        float4 v = x[i];
        xb[i * 2] = (u32)f2bf(v.x) | ((u32)f2bf(v.y) << 16);
        xb[i * 2 + 1] = (u32)f2bf(v.z) | ((u32)f2bf(v.w) << 16);
    }
}

// ---- fused RGCN layer: per block of 32 dst nodes,
// phase 1: per-relation mean of xb[src] accumulated in regs (lane owns cols
//   2l,2l+1), written straight into MFMA A-frag order in LDS (XOR-swizzled:
//   raw frag-order b32 writes are 16-way bank-conflicted; swizzle keeps the
//   phase-2 b128 reads a within-quad permutation -> still conflict-free).
// phase 2: A[32x1152] @ B[1152x128] via 16x16x32 MFMA; wave g owns col-tile
//   g, B-frags read direct from global (288 KB, L2-resident; shared across
//   both mt tiles). Epilogue: +bias, ReLU, store bf16 (h) or f32 (out).
template <bool OUTBF>
__global__ __launch_bounds__(512, 4) void rgcn_fused(const u32* __restrict__ xb,
                                                     const u16* __restrict__ Bf,
                                                     const int* __restrict__ off,
                                                     const u32* __restrict__ epk,
                                                     const float* __restrict__ bias,
                                                     void* __restrict__ outp) {
    __shared__ u32 A32[KT * 2 * 256];  // 73728 B

    const int t = threadIdx.x;
    const int wid = t >> 6;
    const int lane = t & 63;
    const int n0 = blockIdx.x * 32;

    // ---- phase 1 ----
    const int q2 = (lane & 15) >> 2;
    const int ktl = lane >> 4;
    const int xv = q2 | ((ktl & 1) << 2);  // swizzle term (3 bits)

#pragma unroll 1
    for (int ii = 0; ii < 4; ++ii) {
        const int i = wid * 4 + ii;
        const int n = n0 + i;
        const int nc = (n < NN) ? n : (NN - 1);
        int offv = 0;
        if (lane < 9) offv = off[nc * 8 + lane];
        const int e0 = __shfl(offv, 0);
        const int e1 = __shfl(offv, 8);
        u32 epkv = 0u;
        if (e0 + lane < e1) epkv = epk[e0 + lane];

        const int mt = i >> 4;
        const int lrow = i & 15;
        // physical u32 index within tile: ((lrow^xv) + 16*q2)*4 + (lane&3)
        const int wbase = (((lrow ^ xv) + 16 * q2) << 2) + (lane & 3);

#pragma unroll 1
        for (int r = 0; r < 8; ++r) {
            const int se = __shfl(offv, r);
            const int ee = __shfl(offv, r + 1);
            float sx = 0.f, sy = 0.f;
            for (int p = se; p < ee; ++p) {
                const int j = p - e0;
                u32 pk;
                if (j < 64) pk = (u32)__shfl((int)epkv, j);
                else pk = epk[p];
                const u32 v = xb[(size_t)(pk >> 3) * 64 + lane];
                sx += bf2f((u16)(v & 0xFFFFu));
                sy += bf2f((u16)(v >> 16));
            }
            const float inv = (ee > se) ? 1.f / (float)(ee - se) : 0.f;
            const int kt = r * 4 + ktl;
            A32[(kt * 2 + mt) * 256 + wbase] =
                (u32)f2bf(sx * inv) | ((u32)f2bf(sy * inv) << 16);
        }
        // root section: k = 1024 + 2*lane -> kt = 32 + ktl; value = xb row
        A32[((32 + ktl) * 2 + mt) * 256 + wbase] = xb[(size_t)nc * 64 + lane];
    }
    __syncthreads();

    // ---- phase 2 ----
    const int g = wid;
    f32x4 accL = {0.f, 0.f, 0.f, 0.f}, accH = {0.f, 0.f, 0.f, 0.f};
    const u16* bp = Bf + ((size_t)g * 64 + lane) * 8;
    const u16* A16 = (const u16*)A32;
#pragma unroll 4
    for (int kt = 0; kt < KT; ++kt) {
        const bf16x8 b = *(const bf16x8*)(bp + (size_t)kt * 4096);
        const int xvr = (lane >> 4) | ((kt & 1) << 2);
        const int lp = (lane ^ xvr) * 8;
        const bf16x8 a0 = *(const bf16x8*)(A16 + (kt * 2 + 0) * 512 + lp);
        const bf16x8 a1 = *(const bf16x8*)(A16 + (kt * 2 + 1) * 512 + lp);
        accL = __builtin_amdgcn_mfma_f32_16x16x32_bf16(a0, b, accL, 0, 0, 0);
        accH = __builtin_amdgcn_mfma_f32_16x16x32_bf16(a1, b, accH, 0, 0, 0);
    }

    // ---- epilogue: C row=(lane>>4)*4+q (+16 for accH), col=g*16+(lane&15) ----
    const int quad = lane >> 4;
    const int l15 = lane & 15;
    const int col = g * 16 + l15;
    const float bb = bias[col];
#pragma unroll
    for (int q = 0; q < 4; ++q) {
        const int rL = n0 + quad * 4 + q;
        const int rH = rL + 16;
        const float vL = fmaxf(accL[q] + bb, 0.f);
        const float vH = fmaxf(accH[q] + bb, 0.f);
        if (OUTBF) {
            u16* hp = (u16*)outp;
            if (rL < NN) hp[(size_t)rL * D + col] = f2bf(vL);
            if (rH < NN) hp[(size_t)rH * D + col] = f2bf(vH);
        } else {
            float* op = (float*)outp;
            if (rL < NN) op[(size_t)rL * D + col] = vL;
            if (rH < NN) op[(size_t)rH * D + col] = vH;
        }
    }
}

extern "C" void kernel_launch(void* const* d_in, const int* in_sizes, int n_in,
                              void* d_out, int out_size, void* d_ws, size_t ws_size,
                              hipStream_t stream) {
    const float* x = (const float*)d_in[0];
    const int* ei = (const int*)d_in[1];
    const int* et = (const int*)d_in[2];
    const float* w1 = (const float*)d_in[3];
    const float* root1 = (const float*)d_in[4];
    const float* b1 = (const float*)d_in[5];
    const float* w2 = (const float*)d_in[6];
    const float* root2 = (const float*)d_in[7];
    const float* b2 = (const float*)d_in[8];
    float* out = (float*)d_out;

    char* ws = (char*)d_ws;
    int* off    = (int*)(ws + 0);                  // (NR+1) ints
    int* cnt_i  = (int*)(ws + 1600512);            // NR ints (hist input)
    int* cursor = (int*)(ws + 3200512);            // NR ints
    int* bsum   = (int*)(ws + 4800512);            // NSB ints
    u32* epk    = (u32*)(ws + 4804096);            // EE u32 (2.4 MB)
    u32* xb     = (u32*)(ws + 7204096);            // N*64 u32 = 12.8 MB
    u32* h      = (u32*)(ws + 20004096);           // N*64 u32 = 12.8 MB
    u16* Bf1    = (u16*)(ws + 32804096);           // 294912 B
    u16* Bf2    = (u16*)(ws + 33099008);           // 294912 B

    const int* srcp = ei;
    const int* dstp = ei + EE;

    // ---- weight pack + cnt zero, x cast, CSR build ----
    bprep2_kernel<<<144, 256, 0, stream>>>(w1, root1, Bf1, w2, root2, Bf2,
                                           (int4*)cnt_i);
    xcast_kernel<<<(NN * 32 + 255) / 256, 256, 0, stream>>>((const float4*)x, xb);
    hist_kernel<<<(EE + 255) / 256, 256, 0, stream>>>(dstp, et, cnt_i, EE);
    scanA<<<NSB, 256, 0, stream>>>(cnt_i, off, bsum);
    scanBC<<<NSB, 256, 0, stream>>>(off, cursor, bsum);
    place_kernel<<<(EE + 255) / 256, 256, 0, stream>>>(srcp, dstp, et, cursor,
                                                       epk, EE);

    const int fused_blocks = (NN + 31) / 32;  // 1563

    // layer 1: xb -> h (bf16)
    rgcn_fused<true><<<fused_blocks, 512, 0, stream>>>(xb, Bf1, off, epk, b1,
                                                       (void*)h);
    // layer 2: h -> out (fp32)
    rgcn_fused<false><<<fused_blocks, 512, 0, stream>>>(h, Bf2, off, epk, b2,
                                                        (void*)out);
}

// Round 3
// 393.249 us; speedup vs baseline: 1.0428x; 1.0428x over previous
//
#include <hip/hip_runtime.h>

#define NN 50000
#define D 128
#define EE 600000
#define R 8
#define NR (NN * R)            /* segments, key = dst*R + rel (node-major) */
#define SCAN_CHUNK 1024
#define NSB ((NR + SCAN_CHUNK - 1) / SCAN_CHUNK) /* 391 */
#define KT 36                  /* K tiles: (8*128 + 128)/32 */

typedef unsigned short u16;
typedef unsigned int u32;
typedef __attribute__((ext_vector_type(8))) short bf16x8;
typedef __attribute__((ext_vector_type(4))) float f32x4;

__device__ inline u16 f2bf(float f) {
    union { float f; u32 u; } v; v.f = f;
    return (u16)((v.u + 0x7FFFu + ((v.u >> 16) & 1u)) >> 16);
}
__device__ inline float bf2f(u16 h) {
    union { u32 u; float f; } v; v.u = ((u32)h) << 16;
    return v.f;
}

// ---- histogram per segment key = dst*R + rel ----
__global__ __launch_bounds__(256) void hist_kernel(const int* __restrict__ dst,
                                                   const int* __restrict__ et,
                                                   int* __restrict__ cnt, int E) {
    int e = blockIdx.x * 256 + threadIdx.x;
    if (e < E) atomicAdd(&cnt[dst[e] * R + et[e]], 1);
}

// ---- exclusive scan pass A ----
__global__ __launch_bounds__(256) void scanA(const int* __restrict__ cnt,
                                             int* __restrict__ off,
                                             int* __restrict__ bsum) {
    __shared__ int ts[256];
    const int b = blockIdx.x, t = threadIdx.x;
    const int base = b * SCAN_CHUNK + t * 4;
    int v0 = 0, v1 = 0, v2 = 0, v3 = 0;
    if (base + 3 < NR) {
        int4 q = *(const int4*)(cnt + base);
        v0 = q.x; v1 = q.y; v2 = q.z; v3 = q.w;
    } else {
        if (base < NR) v0 = cnt[base];
        if (base + 1 < NR) v1 = cnt[base + 1];
        if (base + 2 < NR) v2 = cnt[base + 2];
    }
    const int s = v0 + v1 + v2 + v3;
    ts[t] = s;
    __syncthreads();
    for (int d = 1; d < 256; d <<= 1) {
        int x = (t >= d) ? ts[t - d] : 0;
        __syncthreads();
        ts[t] += x;
        __syncthreads();
    }
    const int excl = ts[t] - s;
    if (base < NR) off[base] = excl;
    if (base + 1 < NR) off[base + 1] = excl + v0;
    if (base + 2 < NR) off[base + 2] = excl + v0 + v1;
    if (base + 3 < NR) off[base + 3] = excl + v0 + v1 + v2;
    if (t == 255) bsum[b] = ts[255];
}

// ---- scan pass B+C fused ----
__global__ __launch_bounds__(256) void scanBC(int* __restrict__ off,
                                              int* __restrict__ cursor,
                                              const int* __restrict__ bsum) {
    __shared__ int red[256];
    const int b = blockIdx.x, t = threadIdx.x;
    int p = 0;
    for (int i = t; i < b; i += 256) p += bsum[i];
    red[t] = p;
    __syncthreads();
    for (int d = 128; d > 0; d >>= 1) {
        if (t < d) red[t] += red[t + d];
        __syncthreads();
    }
    const int add = red[0];
    const int base = b * SCAN_CHUNK + t * 4;
#pragma unroll
    for (int j = 0; j < 4; ++j)
        if (base + j < NR) {
            int v = off[base + j] + add;
            off[base + j] = v;
            cursor[base + j] = v;
        }
    if (b == 0 && t == 0) off[NR] = EE;
}

// ---- place: ONE packed u32 store per edge: (src << 3) | rel  (src < 2^16) ----
__global__ __launch_bounds__(256) void place_kernel(const int* __restrict__ src,
                                                    const int* __restrict__ dst,
                                                    const int* __restrict__ et,
                                                    int* __restrict__ cursor,
                                                    u32* __restrict__ epk, int E) {
    int e = blockIdx.x * 256 + threadIdx.x;
    if (e < E) {
        int r = et[e];
        int key = dst[e] * R + r;
        int p = atomicAdd(&cursor[key], 1);
        epk[p] = ((u32)src[e] << 3) | (u32)r;
    }
}

// ---- pack both layers' B = [W_1..W_8; root] (K=1152, 128 cols) into MFMA
// B-frag order: [kt(36)][g(8)][lane(64)][j(8)], col = g*16+(lane&15),
// k = kt*32+(lane>>4)*8+j. Also zero cnt_i. ----
__global__ __launch_bounds__(256) void bprep2_kernel(const float* __restrict__ w1,
                                                     const float* __restrict__ root1,
                                                     u16* __restrict__ Bf1,
                                                     const float* __restrict__ w2,
                                                     const float* __restrict__ root2,
                                                     u16* __restrict__ Bf2,
                                                     int4* __restrict__ cntz) {
    int gidx = blockIdx.x * 256 + threadIdx.x;  // over 2*36*8*64 = 36864
    for (int i = gidx; i < NR / 4; i += 36864)
        cntz[i] = make_int4(0, 0, 0, 0);
    if (gidx >= 2 * KT * 8 * 64) return;
    const int layer = gidx / (KT * 8 * 64);
    const int idx = gidx - layer * (KT * 8 * 64);
    const float* w = layer ? w2 : w1;
    const float* root = layer ? root2 : root1;
    u16* Bfrag = layer ? Bf2 : Bf1;
    const int lane = idx & 63;
    const int g = (idx >> 6) & 7;
    const int kt = idx >> 9;  // 0..35
    const int col = g * 16 + (lane & 15);
    const int kbase = kt * 32 + (lane >> 4) * 8;
    u16* o = Bfrag + (size_t)idx * 8;
#pragma unroll
    for (int j = 0; j < 8; ++j) {
        const int k = kbase + j;
        float v = (k < R * D) ? w[(size_t)(k >> 7) * (D * D) + (size_t)(k & 127) * D + col]
                              : root[(size_t)(k - R * D) * D + col];
        o[j] = f2bf(v);
    }
}

// ---- cast x fp32 -> packed bf16 pairs [N][64] u32 ----
__global__ __launch_bounds__(256) void xcast_kernel(const float4* __restrict__ x,
                                                    u32* __restrict__ xb) {
    int i = blockIdx.x * 256 + threadIdx.x;  // over N*32
    if (i < NN * 32) {
        float4 v = x[i];
        xb[i * 2] = (u32)f2bf(v.x) | ((u32)f2bf(v.y) << 16);
        xb[i * 2 + 1] = (u32)f2bf(v.z) | ((u32)f2bf(v.w) << 16);
    }
}

// ---- fused RGCN layer, 32 dst nodes / block, 8 waves ----
// phase 1 (REWORKED round 3): per wave, 4 nodes serially; per node stream the
//   WHOLE edge list (all rels, CSR-contiguous) with 4-wide batched gathers +
//   one-batch lookahead (8 loads in flight). Running (sx,sy,cnt) flushed to
//   the A-frag LDS slot on relation change (wave-uniform branch: pk is
//   broadcast). Replaces 32 branchy dependent per-segment loops -> was
//   latency-bound at VALUBusy 28% / MfmaUtil 4%.
// phase 2: A[32x1152] @ B[1152x128] via 16x16x32 MFMA; wave g owns col-tile
//   g, B-frags read direct from global (288 KB, L2-resident).
template <bool OUTBF>
__global__ __launch_bounds__(512, 4) void rgcn_fused(const u32* __restrict__ xb,
                                                     const u16* __restrict__ Bf,
                                                     const int* __restrict__ off,
                                                     const u32* __restrict__ epk,
                                                     const float* __restrict__ bias,
                                                     void* __restrict__ outp) {
    __shared__ u32 A32[KT * 2 * 256];  // 73728 B

    const int t = threadIdx.x;
    const int wid = t >> 6;
    const int lane = t & 63;
    const int n0 = blockIdx.x * 32;

    const int q2 = (lane & 15) >> 2;
    const int ktl = lane >> 4;
    const int xv = q2 | ((ktl & 1) << 2);  // swizzle term (3 bits)

    // zero A (empty segments must read 0 in phase 2)
    {
        uint4* Az = (uint4*)A32;
        for (int i = t; i < (KT * 2 * 256) / 4; i += 512)
            Az[i] = make_uint4(0, 0, 0, 0);
    }
    __syncthreads();

#define PREF(pk_, va_, pp)                                                    \
    do {                                                                      \
        pk_ = 0u; va_ = 0u;                                                   \
        if ((pp) < e1) {                                                      \
            const int j_ = (pp) - e0;                                         \
            pk_ = (j_ < 64) ? (u32)__shfl((int)epkv, j_) : epk[pp];           \
            va_ = xb[(size_t)(pk_ >> 3) * 64 + lane];                         \
        }                                                                     \
    } while (0)

#define PROC(pk_, va_, pp)                                                    \
    do {                                                                      \
        if ((pp) < e1) {                                                      \
            const int r_ = (int)(pk_ & 7u);                                   \
            if (r_ != cr) {                                                   \
                if (c > 0) {                                                  \
                    const float inv_ = 1.f / (float)c;                        \
                    A32[((cr * 4 + ktl) * 2 + mt) * 256 + wbase] =            \
                        (u32)f2bf(sx * inv_) | ((u32)f2bf(sy * inv_) << 16);  \
                }                                                             \
                cr = r_; sx = 0.f; sy = 0.f; c = 0;                           \
            }                                                                 \
            sx += bf2f((u16)(va_ & 0xFFFFu));                                 \
            sy += bf2f((u16)(va_ >> 16));                                     \
            ++c;                                                              \
        }                                                                     \
    } while (0)

    // ---- phase 1 ----
#pragma unroll 1
    for (int ii = 0; ii < 4; ++ii) {
        const int i = wid * 4 + ii;
        const int n = n0 + i;
        const int nc = (n < NN) ? n : (NN - 1);
        const int mt = i >> 4;
        const int lrow = i & 15;
        const int wbase = (((lrow ^ xv) + 16 * q2) << 2) + (lane & 3);

        // root section: kt = 32 + ktl (prefetches deep, independent)
        const u32 rootv = xb[(size_t)nc * 64 + lane];

        int offv = 0;
        if (lane < 9) offv = off[nc * 8 + lane];
        const int e0 = __shfl(offv, 0);
        const int e1 = __shfl(offv, 8);
        u32 epkv = 0u;
        if (e0 + lane < e1) epkv = epk[e0 + lane];

        A32[((32 + ktl) * 2 + mt) * 256 + wbase] = rootv;

        int cr = -1, c = 0;
        float sx = 0.f, sy = 0.f;

        int p = e0;
        u32 k0, k1, k2, k3, v0, v1, v2, v3;
        PREF(k0, v0, p);
        PREF(k1, v1, p + 1);
        PREF(k2, v2, p + 2);
        PREF(k3, v3, p + 3);
        while (p < e1) {
            const int np = p + 4;
            u32 nk0, nk1, nk2, nk3, nv0, nv1, nv2, nv3;
            PREF(nk0, nv0, np);
            PREF(nk1, nv1, np + 1);
            PREF(nk2, nv2, np + 2);
            PREF(nk3, nv3, np + 3);
            PROC(k0, v0, p);
            PROC(k1, v1, p + 1);
            PROC(k2, v2, p + 2);
            PROC(k3, v3, p + 3);
            p = np;
            k0 = nk0; v0 = nv0; k1 = nk1; v1 = nv1;
            k2 = nk2; v2 = nv2; k3 = nk3; v3 = nv3;
        }
        if (c > 0) {
            const float inv_ = 1.f / (float)c;
            A32[((cr * 4 + ktl) * 2 + mt) * 256 + wbase] =
                (u32)f2bf(sx * inv_) | ((u32)f2bf(sy * inv_) << 16);
        }
    }
#undef PREF
#undef PROC
    __syncthreads();

    // ---- phase 2 ----
    const int g = wid;
    f32x4 accL = {0.f, 0.f, 0.f, 0.f}, accH = {0.f, 0.f, 0.f, 0.f};
    const u16* bp = Bf + ((size_t)g * 64 + lane) * 8;
    const u16* A16 = (const u16*)A32;
#pragma unroll 4
    for (int kt = 0; kt < KT; ++kt) {
        const bf16x8 b = *(const bf16x8*)(bp + (size_t)kt * 4096);
        const int xvr = (lane >> 4) | ((kt & 1) << 2);
        const int lp = (lane ^ xvr) * 8;
        const bf16x8 a0 = *(const bf16x8*)(A16 + (kt * 2 + 0) * 512 + lp);
        const bf16x8 a1 = *(const bf16x8*)(A16 + (kt * 2 + 1) * 512 + lp);
        accL = __builtin_amdgcn_mfma_f32_16x16x32_bf16(a0, b, accL, 0, 0, 0);
        accH = __builtin_amdgcn_mfma_f32_16x16x32_bf16(a1, b, accH, 0, 0, 0);
    }

    // ---- epilogue: C row=(lane>>4)*4+q (+16 for accH), col=g*16+(lane&15) ----
    const int quad = lane >> 4;
    const int l15 = lane & 15;
    const int col = g * 16 + l15;
    const float bb = bias[col];
#pragma unroll
    for (int q = 0; q < 4; ++q) {
        const int rL = n0 + quad * 4 + q;
        const int rH = rL + 16;
        const float vL = fmaxf(accL[q] + bb, 0.f);
        const float vH = fmaxf(accH[q] + bb, 0.f);
        if (OUTBF) {
            u16* hp = (u16*)outp;
            if (rL < NN) hp[(size_t)rL * D + col] = f2bf(vL);
            if (rH < NN) hp[(size_t)rH * D + col] = f2bf(vH);
        } else {
            float* op = (float*)outp;
            if (rL < NN) op[(size_t)rL * D + col] = vL;
            if (rH < NN) op[(size_t)rH * D + col] = vH;
        }
    }
}

extern "C" void kernel_launch(void* const* d_in, const int* in_sizes, int n_in,
                              void* d_out, int out_size, void* d_ws, size_t ws_size,
                              hipStream_t stream) {
    const float* x = (const float*)d_in[0];
    const int* ei = (const int*)d_in[1];
    const int* et = (const int*)d_in[2];
    const float* w1 = (const float*)d_in[3];
    const float* root1 = (const float*)d_in[4];
    const float* b1 = (const float*)d_in[5];
    const float* w2 = (const float*)d_in[6];
    const float* root2 = (const float*)d_in[7];
    const float* b2 = (const float*)d_in[8];
    float* out = (float*)d_out;

    char* ws = (char*)d_ws;
    int* off    = (int*)(ws + 0);                  // (NR+1) ints
    int* cnt_i  = (int*)(ws + 1600512);            // NR ints (hist input)
    int* cursor = (int*)(ws + 3200512);            // NR ints
    int* bsum   = (int*)(ws + 4800512);            // NSB ints
    u32* epk    = (u32*)(ws + 4804096);            // EE u32 (2.4 MB)
    u32* xb     = (u32*)(ws + 7204096);            // N*64 u32 = 12.8 MB
    u32* h      = (u32*)(ws + 20004096);           // N*64 u32 = 12.8 MB
    u16* Bf1    = (u16*)(ws + 32804096);           // 294912 B
    u16* Bf2    = (u16*)(ws + 33099008);           // 294912 B

    const int* srcp = ei;
    const int* dstp = ei + EE;

    // ---- weight pack + cnt zero, x cast, CSR build ----
    bprep2_kernel<<<144, 256, 0, stream>>>(w1, root1, Bf1, w2, root2, Bf2,
                                           (int4*)cnt_i);
    xcast_kernel<<<(NN * 32 + 255) / 256, 256, 0, stream>>>((const float4*)x, xb);
    hist_kernel<<<(EE + 255) / 256, 256, 0, stream>>>(dstp, et, cnt_i, EE);
    scanA<<<NSB, 256, 0, stream>>>(cnt_i, off, bsum);
    scanBC<<<NSB, 256, 0, stream>>>(off, cursor, bsum);
    place_kernel<<<(EE + 255) / 256, 256, 0, stream>>>(srcp, dstp, et, cursor,
                                                       epk, EE);

    const int fused_blocks = (NN + 31) / 32;  // 1563

    // layer 1: xb -> h (bf16)
    rgcn_fused<true><<<fused_blocks, 512, 0, stream>>>(xb, Bf1, off, epk, b1,
                                                       (void*)h);
    // layer 2: h -> out (fp32)
    rgcn_fused<false><<<fused_blocks, 512, 0, stream>>>(h, Bf2, off, epk, b2,
                                                        (void*)out);
}

// Round 4
// 285.271 us; speedup vs baseline: 1.4375x; 1.3785x over previous
//
#include <hip/hip_runtime.h>

#define NN 50000
#define D 128
#define EE 600000
#define R 8
#define NR (NN * R)            /* segments, key = dst*R + rel (node-major) */
#define SCAN_CHUNK 1024
#define NSB ((NR + SCAN_CHUNK - 1) / SCAN_CHUNK) /* 391 */
#define KT 36                  /* K tiles: (8*128 + 128)/32 */

typedef unsigned short u16;
typedef unsigned int u32;
typedef __attribute__((ext_vector_type(8))) short bf16x8;
typedef __attribute__((ext_vector_type(4))) float f32x4;

#define RDL(v_, i_) __builtin_amdgcn_readlane((int)(v_), (i_))

__device__ inline u16 f2bf(float f) {
    union { float f; u32 u; } v; v.f = f;
    return (u16)((v.u + 0x7FFFu + ((v.u >> 16) & 1u)) >> 16);
}
__device__ inline float bf2f(u16 h) {
    union { u32 u; float f; } v; v.u = ((u32)h) << 16;
    return v.f;
}

// ---- pass 1: histogram + per-edge rank (ONE atomic sweep; was hist+place=2) ----
__global__ __launch_bounds__(256) void histrank_kernel(const int* __restrict__ dst,
                                                       const int* __restrict__ et,
                                                       int* __restrict__ cnt,
                                                       int* __restrict__ rk, int E) {
    int e = blockIdx.x * 256 + threadIdx.x;
    if (e < E) rk[e] = atomicAdd(&cnt[dst[e] * R + et[e]], 1);
}

// ---- exclusive scan pass A ----
__global__ __launch_bounds__(256) void scanA(const int* __restrict__ cnt,
                                             int* __restrict__ off,
                                             int* __restrict__ bsum) {
    __shared__ int ts[256];
    const int b = blockIdx.x, t = threadIdx.x;
    const int base = b * SCAN_CHUNK + t * 4;
    int v0 = 0, v1 = 0, v2 = 0, v3 = 0;
    if (base + 3 < NR) {
        int4 q = *(const int4*)(cnt + base);
        v0 = q.x; v1 = q.y; v2 = q.z; v3 = q.w;
    } else {
        if (base < NR) v0 = cnt[base];
        if (base + 1 < NR) v1 = cnt[base + 1];
        if (base + 2 < NR) v2 = cnt[base + 2];
    }
    const int s = v0 + v1 + v2 + v3;
    ts[t] = s;
    __syncthreads();
    for (int d = 1; d < 256; d <<= 1) {
        int x = (t >= d) ? ts[t - d] : 0;
        __syncthreads();
        ts[t] += x;
        __syncthreads();
    }
    const int excl = ts[t] - s;
    if (base < NR) off[base] = excl;
    if (base + 1 < NR) off[base + 1] = excl + v0;
    if (base + 2 < NR) off[base + 2] = excl + v0 + v1;
    if (base + 3 < NR) off[base + 3] = excl + v0 + v1 + v2;
    if (t == 255) bsum[b] = ts[255];
}

// ---- scan pass B+C fused (no cursor mirror needed anymore) ----
__global__ __launch_bounds__(256) void scanBC(int* __restrict__ off,
                                              const int* __restrict__ bsum) {
    __shared__ int red[256];
    const int b = blockIdx.x, t = threadIdx.x;
    int p = 0;
    for (int i = t; i < b; i += 256) p += bsum[i];
    red[t] = p;
    __syncthreads();
    for (int d = 128; d > 0; d >>= 1) {
        if (t < d) red[t] += red[t + d];
        __syncthreads();
    }
    const int add = red[0];
    const int base = b * SCAN_CHUNK + t * 4;
#pragma unroll
    for (int j = 0; j < 4; ++j)
        if (base + j < NR) off[base + j] += add;
    if (b == 0 && t == 0) off[NR] = EE;
}

// ---- pass 2: scatter packed edges, NO atomics: p = off[key] + rank ----
__global__ __launch_bounds__(256) void place2_kernel(const int* __restrict__ src,
                                                     const int* __restrict__ dst,
                                                     const int* __restrict__ et,
                                                     const int* __restrict__ off,
                                                     const int* __restrict__ rk,
                                                     u32* __restrict__ epk, int E) {
    int e = blockIdx.x * 256 + threadIdx.x;
    if (e < E) {
        const int r = et[e];
        const int p = off[dst[e] * R + r] + rk[e];
        epk[p] = ((u32)src[e] << 3) | (u32)r;
    }
}

// ---- pack both layers' B = [W_1..W_8; root] (K=1152, 128 cols) into MFMA
// B-frag order: [kt(36)][g(8)][lane(64)][j(8)], col = g*16+(lane&15),
// k = kt*32+(lane>>4)*8+j. Also zero cnt_i. ----
__global__ __launch_bounds__(256) void bprep2_kernel(const float* __restrict__ w1,
                                                     const float* __restrict__ root1,
                                                     u16* __restrict__ Bf1,
                                                     const float* __restrict__ w2,
                                                     const float* __restrict__ root2,
                                                     u16* __restrict__ Bf2,
                                                     int4* __restrict__ cntz) {
    int gidx = blockIdx.x * 256 + threadIdx.x;  // over 2*36*8*64 = 36864
    for (int i = gidx; i < NR / 4; i += 36864)
        cntz[i] = make_int4(0, 0, 0, 0);
    if (gidx >= 2 * KT * 8 * 64) return;
    const int layer = gidx / (KT * 8 * 64);
    const int idx = gidx - layer * (KT * 8 * 64);
    const float* w = layer ? w2 : w1;
    const float* root = layer ? root2 : root1;
    u16* Bfrag = layer ? Bf2 : Bf1;
    const int lane = idx & 63;
    const int g = (idx >> 6) & 7;
    const int kt = idx >> 9;  // 0..35
    const int col = g * 16 + (lane & 15);
    const int kbase = kt * 32 + (lane >> 4) * 8;
    u16* o = Bfrag + (size_t)idx * 8;
#pragma unroll
    for (int j = 0; j < 8; ++j) {
        const int k = kbase + j;
        float v = (k < R * D) ? w[(size_t)(k >> 7) * (D * D) + (size_t)(k & 127) * D + col]
                              : root[(size_t)(k - R * D) * D + col];
        o[j] = f2bf(v);
    }
}

// ---- cast x fp32 -> packed bf16 pairs [N][64] u32 ----
__global__ __launch_bounds__(256) void xcast_kernel(const float4* __restrict__ x,
                                                    u32* __restrict__ xb) {
    int i = blockIdx.x * 256 + threadIdx.x;  // over N*32
    if (i < NN * 32) {
        float4 v = x[i];
        xb[i * 2] = (u32)f2bf(v.x) | ((u32)f2bf(v.y) << 16);
        xb[i * 2 + 1] = (u32)f2bf(v.z) | ((u32)f2bf(v.w) << 16);
    }
}

// ---- fused RGCN layer, 32 dst nodes / block, 8 waves ----
// phase 1 (round 4): per wave ONE contiguous edge stream covering its 4
//   nodes' 32 segments (CSR is node-major). ALL loads unconditional
//   (addresses clamped) so the backend keeps counted vmcnt -- round 3's
//   per-load `if (pp<e1)` conditionals forced conservative waitcnt drains
//   and serialized the gathers (125us @ VALUBusy 33%). Loop state
//   (p/seg/segEnd) is SGPR (readlane-derived), so all branches are
//   s_cbranch: no exec churn, no load predication. 3-batch rotation keeps
//   12 gathers + window loads in flight. Segment mean flushed into the
//   MFMA A-frag LDS slot at scalar boundary checks.
// phase 2: A[32x1152] @ B[1152x128] via 16x16x32 MFMA; wave g owns col-tile
//   g, B-frags read direct from global (288 KB, L2-resident).
template <bool OUTBF>
__global__ __launch_bounds__(512, 4) void rgcn_fused(const u32* __restrict__ xb,
                                                     const u16* __restrict__ Bf,
                                                     const int* __restrict__ off,
                                                     const u32* __restrict__ epk,
                                                     const float* __restrict__ bias,
                                                     void* __restrict__ outp) {
    __shared__ u32 A32[KT * 2 * 256];  // 73728 B

    const int t = threadIdx.x;
    const int wid = t >> 6;
    const int lane = t & 63;
    const int n0 = blockIdx.x * 32;

    const int q2 = (lane & 15) >> 2;
    const int ktl = lane >> 4;
    const int xv = q2 | ((ktl & 1) << 2);  // swizzle term (3 bits)

    // zero A (empty segments must read 0 in phase 2)
    {
        uint4* Az = (uint4*)A32;
        for (int i = t; i < (KT * 2 * 256) / 4; i += 512)
            Az[i] = make_uint4(0, 0, 0, 0);
    }
    __syncthreads();

    const int i0 = wid * 4;        // first of this wave's 4 node slots
    const int nb = n0 + i0;

    // off window: 33 boundaries for 4 nodes, one unconditional clamped load
    int offv;
    {
        int oi = nb * 8 + lane;
        if (oi > NR) oi = NR;      // off[NR] = EE; OOB nodes -> empty segs
        offv = off[oi];
    }
    const int e0 = RDL(offv, 0);
    const int e1 = RDL(offv, 32);

    // root rows for the 4 nodes (independent loads, issued early)
    u32 rv0, rv1, rv2, rv3;
    {
        int c0 = (nb < NN) ? nb : (NN - 1);
        int c1 = (nb + 1 < NN) ? nb + 1 : (NN - 1);
        int c2 = (nb + 2 < NN) ? nb + 2 : (NN - 1);
        int c3 = (nb + 3 < NN) ? nb + 3 : (NN - 1);
        rv0 = xb[(size_t)c0 * 64 + lane];
        rv1 = xb[(size_t)c1 * 64 + lane];
        rv2 = xb[(size_t)c2 * 64 + lane];
        rv3 = xb[(size_t)c3 * 64 + lane];
    }

    // sliding 128-edge epk window in 2 regs (unconditional clamped loads)
    int wb = e0;
    u32 w0, w1;
    {
        int ia = e0 + lane; if (ia >= EE) ia = EE - 1;
        int ib = e0 + 64 + lane; if (ib >= EE) ib = EE - 1;
        w0 = epk[ia];
        w1 = epk[ib];
    }

    // segment state (all scalar)
    int seg = 0;
    while (seg < 32 && RDL(offv, seg + 1) <= e0) ++seg;
    int segEnd = (seg < 32) ? RDL(offv, seg + 1) : 0x7FFFFFFF;
    int segStart = e0;
    float sx = 0.f, sy = 0.f;

#define FLUSH(pp)                                                              \
    do {                                                                       \
        const float inv_ = 1.f / (float)((pp) - segStart);                     \
        const int i_ = i0 + (seg >> 3);                                        \
        const int mt_ = i_ >> 4;                                               \
        const int wb_ = ((((i_ & 15) ^ xv) + 16 * q2) << 2) + (lane & 3);      \
        A32[(((seg & 7) * 4 + ktl) * 2 + mt_) * 256 + wb_] =                   \
            (u32)f2bf(sx * inv_) | ((u32)f2bf(sy * inv_) << 16);               \
        sx = 0.f; sy = 0.f; segStart = (pp);                                   \
        ++seg;                                                                 \
        while (seg < 32 && RDL(offv, seg + 1) <= (pp)) ++seg;                  \
        segEnd = (seg < 32) ? RDL(offv, seg + 1) : 0x7FFFFFFF;                 \
    } while (0)

#define PREF1(d_, pp)                                                          \
    do {                                                                       \
        const int j_ = (pp) - wb;                                              \
        const u32 pk_ = (u32)((j_ < 64) ? RDL(w0, j_) : RDL(w1, j_ - 64));     \
        d_ = xb[(size_t)(pk_ >> 3) * 64 + lane];                               \
    } while (0)

#define PROC1(v_, pp)                                                          \
    do {                                                                       \
        if ((pp) == segEnd) FLUSH(pp);                                         \
        if ((pp) < e1) {                                                       \
            sx += bf2f((u16)((v_) & 0xFFFFu));                                 \
            sy += bf2f((u16)((v_) >> 16));                                     \
        }                                                                      \
    } while (0)

    // ---- edge stream: batches of 4, 3 batches in flight ----
    int p = e0;
    u32 a0, a1, a2, a3, b0, b1, b2, b3, c0, c1, c2, c3;
    PREF1(a0, p);     PREF1(a1, p + 1); PREF1(a2, p + 2); PREF1(a3, p + 3);
    PREF1(b0, p + 4); PREF1(b1, p + 5); PREF1(b2, p + 6); PREF1(b3, p + 7);
    const int nbt = (e1 - e0 + 3) >> 2;
#pragma unroll 1
    for (int bt = 0; bt < nbt; ++bt) {
        if (p + 8 - wb >= 64) {  // slide window (w1 not read again for >=12 edges)
            wb += 64; w0 = w1;
            int ia = wb + 64 + lane; if (ia >= EE) ia = EE - 1;
            w1 = epk[ia];
        }
        PREF1(c0, p + 8); PREF1(c1, p + 9); PREF1(c2, p + 10); PREF1(c3, p + 11);
        PROC1(a0, p); PROC1(a1, p + 1); PROC1(a2, p + 2); PROC1(a3, p + 3);
        p += 4;
        a0 = b0; a1 = b1; a2 = b2; a3 = b3;
        b0 = c0; b1 = c1; b2 = c2; b3 = c3;
    }
    if (seg < 32 && segStart < e1) FLUSH(e1);  // final open segment

#undef FLUSH
#undef PREF1
#undef PROC1

    // root section: kt = 32 + ktl
    {
#pragma unroll
        for (int k = 0; k < 4; ++k) {
            const int ii = i0 + k;
            const int mt_ = ii >> 4;
            const int wb_ = ((((ii & 15) ^ xv) + 16 * q2) << 2) + (lane & 3);
            const u32 rv = (k == 0) ? rv0 : (k == 1) ? rv1 : (k == 2) ? rv2 : rv3;
            A32[((32 + ktl) * 2 + mt_) * 256 + wb_] = rv;
        }
    }
    __syncthreads();

    // ---- phase 2 ----
    const int g = wid;
    f32x4 accL = {0.f, 0.f, 0.f, 0.f}, accH = {0.f, 0.f, 0.f, 0.f};
    const u16* bp = Bf + ((size_t)g * 64 + lane) * 8;
    const u16* A16 = (const u16*)A32;
#pragma unroll 4
    for (int kt = 0; kt < KT; ++kt) {
        const bf16x8 b = *(const bf16x8*)(bp + (size_t)kt * 4096);
        const int xvr = (lane >> 4) | ((kt & 1) << 2);
        const int lp = (lane ^ xvr) * 8;
        const bf16x8 fa0 = *(const bf16x8*)(A16 + (kt * 2 + 0) * 512 + lp);
        const bf16x8 fa1 = *(const bf16x8*)(A16 + (kt * 2 + 1) * 512 + lp);
        accL = __builtin_amdgcn_mfma_f32_16x16x32_bf16(fa0, b, accL, 0, 0, 0);
        accH = __builtin_amdgcn_mfma_f32_16x16x32_bf16(fa1, b, accH, 0, 0, 0);
    }

    // ---- epilogue: C row=(lane>>4)*4+q (+16 for accH), col=g*16+(lane&15) ----
    const int quad = lane >> 4;
    const int l15 = lane & 15;
    const int col = g * 16 + l15;
    const float bb = bias[col];
#pragma unroll
    for (int q = 0; q < 4; ++q) {
        const int rL = n0 + quad * 4 + q;
        const int rH = rL + 16;
        const float vL = fmaxf(accL[q] + bb, 0.f);
        const float vH = fmaxf(accH[q] + bb, 0.f);
        if (OUTBF) {
            u16* hp = (u16*)outp;
            if (rL < NN) hp[(size_t)rL * D + col] = f2bf(vL);
            if (rH < NN) hp[(size_t)rH * D + col] = f2bf(vH);
        } else {
            float* op = (float*)outp;
            if (rL < NN) op[(size_t)rL * D + col] = vL;
            if (rH < NN) op[(size_t)rH * D + col] = vH;
        }
    }
}

extern "C" void kernel_launch(void* const* d_in, const int* in_sizes, int n_in,
                              void* d_out, int out_size, void* d_ws, size_t ws_size,
                              hipStream_t stream) {
    const float* x = (const float*)d_in[0];
    const int* ei = (const int*)d_in[1];
    const int* et = (const int*)d_in[2];
    const float* w1 = (const float*)d_in[3];
    const float* root1 = (const float*)d_in[4];
    const float* b1 = (const float*)d_in[5];
    const float* w2 = (const float*)d_in[6];
    const float* root2 = (const float*)d_in[7];
    const float* b2 = (const float*)d_in[8];
    float* out = (float*)d_out;

    char* ws = (char*)d_ws;
    int* off    = (int*)(ws + 0);                  // (NR+1) ints
    int* cnt_i  = (int*)(ws + 1600512);            // NR ints
    int* rk     = (int*)(ws + 3200512);            // EE ints (edge rank)
    int* bsum   = (int*)(ws + 5600512);            // NSB ints
    u32* epk    = (u32*)(ws + 5604096);            // EE u32 (2.4 MB)
    u32* xb     = (u32*)(ws + 8004096);            // N*64 u32 = 12.8 MB
    u32* h      = (u32*)(ws + 20804096);           // N*64 u32 = 12.8 MB
    u16* Bf1    = (u16*)(ws + 33604096);           // 294912 B
    u16* Bf2    = (u16*)(ws + 33899008);           // 294912 B

    const int* srcp = ei;
    const int* dstp = ei + EE;

    // ---- weight pack + cnt zero, x cast, CSR build (1 atomic pass) ----
    bprep2_kernel<<<144, 256, 0, stream>>>(w1, root1, Bf1, w2, root2, Bf2,
                                           (int4*)cnt_i);
    xcast_kernel<<<(NN * 32 + 255) / 256, 256, 0, stream>>>((const float4*)x, xb);
    histrank_kernel<<<(EE + 255) / 256, 256, 0, stream>>>(dstp, et, cnt_i, rk, EE);
    scanA<<<NSB, 256, 0, stream>>>(cnt_i, off, bsum);
    scanBC<<<NSB, 256, 0, stream>>>(off, bsum);
    place2_kernel<<<(EE + 255) / 256, 256, 0, stream>>>(srcp, dstp, et, off, rk,
                                                        epk, EE);

    const int fused_blocks = (NN + 31) / 32;  // 1563

    // layer 1: xb -> h (bf16)
    rgcn_fused<true><<<fused_blocks, 512, 0, stream>>>(xb, Bf1, off, epk, b1,
                                                       (void*)h);
    // layer 2: h -> out (fp32)
    rgcn_fused<false><<<fused_blocks, 512, 0, stream>>>(h, Bf2, off, epk, b2,
                                                        (void*)out);
}

// Round 5
// 252.383 us; speedup vs baseline: 1.6248x; 1.1303x over previous
//
#include <hip/hip_runtime.h>

#define NN 50000
#define D 128
#define EE 600000
#define R 8
#define NR (NN * R)            /* segments, key = dst*R + rel (node-major) */
#define SCAN_CHUNK 1024
#define NSB ((NR + SCAN_CHUNK - 1) / SCAN_CHUNK) /* 391 */
#define KT 36                  /* K tiles: (8*128 + 128)/32 */

typedef unsigned short u16;
typedef unsigned int u32;
typedef __attribute__((ext_vector_type(8))) short bf16x8;
typedef __attribute__((ext_vector_type(4))) float f32x4;

#define RDL(v_, i_) __builtin_amdgcn_readlane((int)(v_), (i_))

__device__ inline u16 f2bf(float f) {
    union { float f; u32 u; } v; v.f = f;
    return (u16)((v.u + 0x7FFFu + ((v.u >> 16) & 1u)) >> 16);
}
__device__ inline float bf2f(u16 h) {
    union { u32 u; float f; } v; v.u = ((u32)h) << 16;
    return v.f;
}

// ---- pass 1 (merged round 5): cast x fp32->bf16 pairs AND histogram+rank.
// Independent work co-issued in one dispatch: overlapped latency, one less
// launch gap. cnt must be zeroed beforehand (bprep2). grid = NN*32/256 = 6250.
__global__ __launch_bounds__(256) void prep2_kernel(const float4* __restrict__ x,
                                                    u32* __restrict__ xb,
                                                    const int* __restrict__ dst,
                                                    const int* __restrict__ et,
                                                    int* __restrict__ cnt,
                                                    int* __restrict__ rk) {
    const int i = blockIdx.x * 256 + threadIdx.x;  // < NN*32 exactly
    const float4 v = x[i];
    if (i < EE) rk[i] = atomicAdd(&cnt[dst[i] * R + et[i]], 1);
    xb[i * 2] = (u32)f2bf(v.x) | ((u32)f2bf(v.y) << 16);
    xb[i * 2 + 1] = (u32)f2bf(v.z) | ((u32)f2bf(v.w) << 16);
}

// ---- exclusive scan pass A ----
__global__ __launch_bounds__(256) void scanA(const int* __restrict__ cnt,
                                             int* __restrict__ off,
                                             int* __restrict__ bsum) {
    __shared__ int ts[256];
    const int b = blockIdx.x, t = threadIdx.x;
    const int base = b * SCAN_CHUNK + t * 4;
    int v0 = 0, v1 = 0, v2 = 0, v3 = 0;
    if (base + 3 < NR) {
        int4 q = *(const int4*)(cnt + base);
        v0 = q.x; v1 = q.y; v2 = q.z; v3 = q.w;
    } else {
        if (base < NR) v0 = cnt[base];
        if (base + 1 < NR) v1 = cnt[base + 1];
        if (base + 2 < NR) v2 = cnt[base + 2];
    }
    const int s = v0 + v1 + v2 + v3;
    ts[t] = s;
    __syncthreads();
    for (int d = 1; d < 256; d <<= 1) {
        int x = (t >= d) ? ts[t - d] : 0;
        __syncthreads();
        ts[t] += x;
        __syncthreads();
    }
    const int excl = ts[t] - s;
    if (base < NR) off[base] = excl;
    if (base + 1 < NR) off[base + 1] = excl + v0;
    if (base + 2 < NR) off[base + 2] = excl + v0 + v1;
    if (base + 3 < NR) off[base + 3] = excl + v0 + v1 + v2;
    if (t == 255) bsum[b] = ts[255];
}

// ---- scan pass B+C fused ----
__global__ __launch_bounds__(256) void scanBC(int* __restrict__ off,
                                              const int* __restrict__ bsum) {
    __shared__ int red[256];
    const int b = blockIdx.x, t = threadIdx.x;
    int p = 0;
    for (int i = t; i < b; i += 256) p += bsum[i];
    red[t] = p;
    __syncthreads();
    for (int d = 128; d > 0; d >>= 1) {
        if (t < d) red[t] += red[t + d];
        __syncthreads();
    }
    const int add = red[0];
    const int base = b * SCAN_CHUNK + t * 4;
#pragma unroll
    for (int j = 0; j < 4; ++j)
        if (base + j < NR) off[base + j] += add;
    if (b == 0 && t == 0) off[NR] = EE;
}

// ---- pass 2: scatter packed edges, NO atomics: p = off[key] + rank ----
__global__ __launch_bounds__(256) void place2_kernel(const int* __restrict__ src,
                                                     const int* __restrict__ dst,
                                                     const int* __restrict__ et,
                                                     const int* __restrict__ off,
                                                     const int* __restrict__ rk,
                                                     u32* __restrict__ epk, int E) {
    int e = blockIdx.x * 256 + threadIdx.x;
    if (e < E) {
        const int r = et[e];
        const int p = off[dst[e] * R + r] + rk[e];
        epk[p] = ((u32)src[e] << 3) | (u32)r;
    }
}

// ---- pack both layers' B = [W_1..W_8; root] (K=1152, 128 cols) into MFMA
// B-frag order: [kt(36)][g(8)][lane(64)][j(8)], col = g*16+(lane&15),
// k = kt*32+(lane>>4)*8+j. Also zero cnt_i (must precede prep2). ----
__global__ __launch_bounds__(256) void bprep2_kernel(const float* __restrict__ w1,
                                                     const float* __restrict__ root1,
                                                     u16* __restrict__ Bf1,
                                                     const float* __restrict__ w2,
                                                     const float* __restrict__ root2,
                                                     u16* __restrict__ Bf2,
                                                     int4* __restrict__ cntz) {
    int gidx = blockIdx.x * 256 + threadIdx.x;  // over 2*36*8*64 = 36864
    for (int i = gidx; i < NR / 4; i += 36864)
        cntz[i] = make_int4(0, 0, 0, 0);
    if (gidx >= 2 * KT * 8 * 64) return;
    const int layer = gidx / (KT * 8 * 64);
    const int idx = gidx - layer * (KT * 8 * 64);
    const float* w = layer ? w2 : w1;
    const float* root = layer ? root2 : root1;
    u16* Bfrag = layer ? Bf2 : Bf1;
    const int lane = idx & 63;
    const int g = (idx >> 6) & 7;
    const int kt = idx >> 9;  // 0..35
    const int col = g * 16 + (lane & 15);
    const int kbase = kt * 32 + (lane >> 4) * 8;
    u16* o = Bfrag + (size_t)idx * 8;
#pragma unroll
    for (int j = 0; j < 8; ++j) {
        const int k = kbase + j;
        float v = (k < R * D) ? w[(size_t)(k >> 7) * (D * D) + (size_t)(k & 127) * D + col]
                              : root[(size_t)(k - R * D) * D + col];
        o[j] = f2bf(v);
    }
}

// ---- fused RGCN layer (round 5: 16 dst nodes / block, 8 waves) ----
// Parallelism was the limiter (round 4: 12.5k waves x 48-edge serial chains,
// LDS 73.7KB -> 2 blocks/CU, occupancy 35%, VALUBusy 43%). Halved tile:
// A-panel LDS 36.9KB -> 4 blocks/CU (32 waves/CU cap), 3125 blocks = 25k
// waves, 2 nodes (~24 edges) serial per wave. Phase-2 B-frags re-read 2x
// from L2 (~900MB @ 34.5TB/s ~ 26us, overlapped) -- accepted trade.
// phase 1: per wave ONE contiguous edge stream for its 2 nodes' 16 segments;
//   ALL loads unconditional (clamped addrs, counted vmcnt preserved); scalar
//   (SGPR/readlane) loop state -> s_cbranch only; 3-batch x4 rotation = 12
//   gathers in flight; mean flushed to A-frag LDS slot at scalar boundaries.
// phase 2: A[16x1152] @ B[1152x128]; wave g owns col-tile g; B-frags direct
//   from global (L2-resident).
template <bool OUTBF>
__global__ __launch_bounds__(512, 8) void rgcn_fused(const u32* __restrict__ xb,
                                                     const u16* __restrict__ Bf,
                                                     const int* __restrict__ off,
                                                     const u32* __restrict__ epk,
                                                     const float* __restrict__ bias,
                                                     void* __restrict__ outp) {
    __shared__ u32 A32[KT * 256];  // 36864 B

    const int t = threadIdx.x;
    const int wid = t >> 6;
    const int lane = t & 63;
    const int n0 = blockIdx.x * 16;

    const int q2 = (lane & 15) >> 2;
    const int ktl = lane >> 4;
    const int xv = q2 | ((ktl & 1) << 2);  // swizzle term (3 bits)

    // zero A (empty segments must read 0 in phase 2)
    {
        uint4* Az = (uint4*)A32;
        for (int i = t; i < (KT * 256) / 4; i += 512)
            Az[i] = make_uint4(0, 0, 0, 0);
    }
    __syncthreads();

    const int i0 = wid * 2;        // first of this wave's 2 node slots
    const int nb = n0 + i0;        // always < NN (50000 = 16*3125, no tail)

    // off window: 17 boundaries for 2 nodes, one unconditional clamped load
    int offv;
    {
        int oi = nb * 8 + lane;
        if (oi > NR) oi = NR;      // off[NR] = EE
        offv = off[oi];
    }
    const int e0 = RDL(offv, 0);
    const int e1 = RDL(offv, 16);

    // root rows (independent, issued early)
    const u32 rv0 = xb[(size_t)nb * 64 + lane];
    const u32 rv1 = xb[(size_t)(nb + 1) * 64 + lane];

    // sliding 128-edge epk window in 2 regs (unconditional clamped loads)
    int wb = e0;
    u32 w0, w1;
    {
        int ia = e0 + lane; if (ia >= EE) ia = EE - 1;
        int ib = e0 + 64 + lane; if (ib >= EE) ib = EE - 1;
        w0 = epk[ia];
        w1 = epk[ib];
    }

    // segment state (all scalar)
    int seg = 0;
    while (seg < 16 && RDL(offv, seg + 1) <= e0) ++seg;
    int segEnd = (seg < 16) ? RDL(offv, seg + 1) : 0x7FFFFFFF;
    int segStart = e0;
    float sx = 0.f, sy = 0.f;

#define FLUSH(pp)                                                              \
    do {                                                                       \
        const float inv_ = 1.f / (float)((pp) - segStart);                     \
        const int i_ = i0 + (seg >> 3);                                        \
        const int wb_ = (((i_ ^ xv) + 16 * q2) << 2) + (lane & 3);             \
        A32[((seg & 7) * 4 + ktl) * 256 + wb_] =                               \
            (u32)f2bf(sx * inv_) | ((u32)f2bf(sy * inv_) << 16);               \
        sx = 0.f; sy = 0.f; segStart = (pp);                                   \
        ++seg;                                                                 \
        while (seg < 16 && RDL(offv, seg + 1) <= (pp)) ++seg;                  \
        segEnd = (seg < 16) ? RDL(offv, seg + 1) : 0x7FFFFFFF;                 \
    } while (0)

#define PREF1(d_, pp)                                                          \
    do {                                                                       \
        const int j_ = (pp) - wb;                                              \
        const u32 pk_ = (u32)((j_ < 64) ? RDL(w0, j_) : RDL(w1, j_ - 64));     \
        d_ = xb[(size_t)(pk_ >> 3) * 64 + lane];                               \
    } while (0)

#define PROC1(v_, pp)                                                          \
    do {                                                                       \
        if ((pp) == segEnd) FLUSH(pp);                                         \
        if ((pp) < e1) {                                                       \
            union { u32 u; float f; } lo_, hi_;                                \
            lo_.u = (v_) << 16;                                                \
            hi_.u = (v_) & 0xFFFF0000u;                                        \
            sx += lo_.f;                                                       \
            sy += hi_.f;                                                       \
        }                                                                      \
    } while (0)

    // ---- edge stream: batches of 4, 3 batches in flight ----
    int p = e0;
    u32 a0, a1, a2, a3, b0, b1, b2, b3, c0, c1, c2, c3;
    PREF1(a0, p);     PREF1(a1, p + 1); PREF1(a2, p + 2); PREF1(a3, p + 3);
    PREF1(b0, p + 4); PREF1(b1, p + 5); PREF1(b2, p + 6); PREF1(b3, p + 7);
    const int nbt = (e1 - e0 + 3) >> 2;
#pragma unroll 1
    for (int bt = 0; bt < nbt; ++bt) {
        if (p + 8 - wb >= 64) {  // slide window
            wb += 64; w0 = w1;
            int ia = wb + 64 + lane; if (ia >= EE) ia = EE - 1;
            w1 = epk[ia];
        }
        PREF1(c0, p + 8); PREF1(c1, p + 9); PREF1(c2, p + 10); PREF1(c3, p + 11);
        PROC1(a0, p); PROC1(a1, p + 1); PROC1(a2, p + 2); PROC1(a3, p + 3);
        p += 4;
        a0 = b0; a1 = b1; a2 = b2; a3 = b3;
        b0 = c0; b1 = c1; b2 = c2; b3 = c3;
    }
    if (seg < 16 && segStart < e1) FLUSH(e1);  // final open segment

#undef FLUSH
#undef PREF1
#undef PROC1

    // root section: kt = 32 + ktl
    {
        const int wb0 = (((i0 ^ xv) + 16 * q2) << 2) + (lane & 3);
        const int wb1 = ((((i0 + 1) ^ xv) + 16 * q2) << 2) + (lane & 3);
        A32[(32 + ktl) * 256 + wb0] = rv0;
        A32[(32 + ktl) * 256 + wb1] = rv1;
    }
    __syncthreads();

    // ---- phase 2: wave g -> col-tile g, 36 MFMA ----
    const int g = wid;
    f32x4 acc = {0.f, 0.f, 0.f, 0.f};
    const u16* bp = Bf + ((size_t)g * 64 + lane) * 8;
    const u16* A16 = (const u16*)A32;
#pragma unroll 4
    for (int kt = 0; kt < KT; ++kt) {
        const bf16x8 b = *(const bf16x8*)(bp + (size_t)kt * 4096);
        const int xvr = (lane >> 4) | ((kt & 1) << 2);
        const int lp = (lane ^ xvr) * 8;
        const bf16x8 fa = *(const bf16x8*)(A16 + kt * 512 + lp);
        acc = __builtin_amdgcn_mfma_f32_16x16x32_bf16(fa, b, acc, 0, 0, 0);
    }

    // ---- epilogue: C row=(lane>>4)*4+q, col=g*16+(lane&15); no tail ----
    const int quad = lane >> 4;
    const int l15 = lane & 15;
    const int col = g * 16 + l15;
    const float bb = bias[col];
#pragma unroll
    for (int q = 0; q < 4; ++q) {
        const int row = n0 + quad * 4 + q;
        const float v = fmaxf(acc[q] + bb, 0.f);
        if (OUTBF)
            ((u16*)outp)[(size_t)row * D + col] = f2bf(v);
        else
            ((float*)outp)[(size_t)row * D + col] = v;
    }
}

extern "C" void kernel_launch(void* const* d_in, const int* in_sizes, int n_in,
                              void* d_out, int out_size, void* d_ws, size_t ws_size,
                              hipStream_t stream) {
    const float* x = (const float*)d_in[0];
    const int* ei = (const int*)d_in[1];
    const int* et = (const int*)d_in[2];
    const float* w1 = (const float*)d_in[3];
    const float* root1 = (const float*)d_in[4];
    const float* b1 = (const float*)d_in[5];
    const float* w2 = (const float*)d_in[6];
    const float* root2 = (const float*)d_in[7];
    const float* b2 = (const float*)d_in[8];
    float* out = (float*)d_out;

    char* ws = (char*)d_ws;
    int* off    = (int*)(ws + 0);                  // (NR+1) ints
    int* cnt_i  = (int*)(ws + 1600512);            // NR ints
    int* rk     = (int*)(ws + 3200512);            // EE ints (edge rank)
    int* bsum   = (int*)(ws + 5600512);            // NSB ints
    u32* epk    = (u32*)(ws + 5604096);            // EE u32 (2.4 MB)
    u32* xb     = (u32*)(ws + 8004096);            // N*64 u32 = 12.8 MB
    u32* h      = (u32*)(ws + 20804096);           // N*64 u32 = 12.8 MB
    u16* Bf1    = (u16*)(ws + 33604096);           // 294912 B
    u16* Bf2    = (u16*)(ws + 33899008);           // 294912 B

    const int* srcp = ei;
    const int* dstp = ei + EE;

    // ---- prep: pack B + zero cnt; then {xcast ∥ hist+rank}; scan; place ----
    bprep2_kernel<<<144, 256, 0, stream>>>(w1, root1, Bf1, w2, root2, Bf2,
                                           (int4*)cnt_i);
    prep2_kernel<<<NN * 32 / 256, 256, 0, stream>>>((const float4*)x, xb,
                                                    dstp, et, cnt_i, rk);
    scanA<<<NSB, 256, 0, stream>>>(cnt_i, off, bsum);
    scanBC<<<NSB, 256, 0, stream>>>(off, bsum);
    place2_kernel<<<(EE + 255) / 256, 256, 0, stream>>>(srcp, dstp, et, off, rk,
                                                        epk, EE);

    const int fused_blocks = NN / 16;  // 3125, exact

    // layer 1: xb -> h (bf16)
    rgcn_fused<true><<<fused_blocks, 512, 0, stream>>>(xb, Bf1, off, epk, b1,
                                                       (void*)h);
    // layer 2: h -> out (fp32)
    rgcn_fused<false><<<fused_blocks, 512, 0, stream>>>(h, Bf2, off, epk, b2,
                                                        (void*)out);
}